// Round 9
// baseline (167.765 us; speedup 1.0000x reference)
//
#include <hip/hip_runtime.h>
#include <hip/hip_bf16.h>
#include <stdint.h>

#define D_MODEL 1024
#define NHEAD 8
#define HDIM 128
#define BATCH 2
#define SEQ 2048
#define MTOT (BATCH*SEQ)   // 4096
#define KVBLK 64
#define NT (SEQ/KVBLK)     // 32

typedef __attribute__((ext_vector_type(4))) float f32x4;
typedef __attribute__((ext_vector_type(8))) short bf16x8;

// XOR swizzle: LDS(row, c) holds element (row, c ^ ((row&7)<<4)). Involution,
// used identically on the pre-swizzled global source (gload16 path) or the
// ds_write dest (reg-staged path), and on the ds_read side (G21).
__device__ __forceinline__ uint32_t swz128(uint32_t row, uint32_t cb) {
  return row * 128u + (cb ^ ((row & 7u) << 4));
}
__device__ __forceinline__ uint32_t swz256(uint32_t row, uint32_t cb) {
  return row * 256u + (cb ^ ((row & 7u) << 4));
}

// async global->LDS, 16B per lane
__device__ __forceinline__ void gload16(void* lds, const void* g) {
  __builtin_amdgcn_global_load_lds(
      reinterpret_cast<const __attribute__((address_space(1))) uint32_t*>(
          reinterpret_cast<uintptr_t>(g)),
      reinterpret_cast<__attribute__((address_space(3))) uint32_t*>(
          (uint32_t)reinterpret_cast<uintptr_t>(lds)),
      16, 0, 0);
}

// Counted barriers (T4).
__device__ __forceinline__ void barrier_lgkm() {
  asm volatile("s_waitcnt lgkmcnt(0)\n\ts_barrier" ::: "memory");
}
__device__ __forceinline__ void barrier_vm16() {
  asm volatile("s_waitcnt vmcnt(16) lgkmcnt(0)\n\ts_barrier" ::: "memory");
}
__device__ __forceinline__ void barrier_vm0() {
  asm volatile("s_waitcnt vmcnt(0) lgkmcnt(0)\n\ts_barrier" ::: "memory");
}

__device__ __forceinline__ bf16x8 cvt8(const float4& a, const float4& b) {
  __hip_bfloat16 o[8] = {__float2bfloat16(a.x), __float2bfloat16(a.y),
                         __float2bfloat16(a.z), __float2bfloat16(a.w),
                         __float2bfloat16(b.x), __float2bfloat16(b.y),
                         __float2bfloat16(b.z), __float2bfloat16(b.w)};
  return *reinterpret_cast<const bf16x8*>(o);
}

// ---------------- transpose+cast all four weights in one launch ----------------
__global__ __launch_bounds__(256)
void transpose4(const float* __restrict__ s0, const float* __restrict__ s1,
                const float* __restrict__ s2, const float* __restrict__ s3,
                __hip_bfloat16* __restrict__ d0, __hip_bfloat16* __restrict__ d1,
                __hip_bfloat16* __restrict__ d2, __hip_bfloat16* __restrict__ d3) {
  const float* W = blockIdx.z == 0 ? s0 : blockIdx.z == 1 ? s1 : blockIdx.z == 2 ? s2 : s3;
  __hip_bfloat16* Wt = blockIdx.z == 0 ? d0 : blockIdx.z == 1 ? d1 : blockIdx.z == 2 ? d2 : d3;
  __shared__ float t[32][33];
  const int x = threadIdx.x, y = threadIdx.y;
  const int n0 = blockIdx.x * 32, k0 = blockIdx.y * 32;
#pragma unroll
  for (int i = 0; i < 4; ++i)
    t[y + i * 8][x] = W[(size_t)(k0 + y + i * 8) * D_MODEL + n0 + x];
  __syncthreads();
#pragma unroll
  for (int i = 0; i < 4; ++i)
    Wt[(size_t)(n0 + y + i * 8) * D_MODEL + k0 + x] = __float2bfloat16(t[x][y + i * 8]);
}

struct GemmArgs {
  const void* A;             // [M][K]  fp32 if AFP32 else bf16
  const __hip_bfloat16* B;   // [N][K]  (W^T)
  const float* bias;         // [N]
  void* out;
  int mode;  // 0: bf16 [bh][s][hd]; 1: bf16 [bh][hd][s]; 2: fp32 [row][col]
};

// ---------------- 128x128 bf16 GEMM, double-buffered prefetch K-loop ----------------
// 256 thr / 4 waves, BK=64, LDS 64KB (2 dbuf x (A 16KB | B 16KB)).
// AFP32: A is fp32 in global; reg-staged (load fp32 early -> MFMA kt -> cvt +
// swizzled ds_write late, T14). Fuses the cast pass into the GEMM.
// else: A bf16 via gload16 with pre-swizzled source (r8-proven path).
template <bool AFP32>
__global__ __launch_bounds__(256)
void gemm_gl(GemmArgs g0, GemmArgs g1, GemmArgs g2, int K) {
  __shared__ char lds[2][32768];   // per buf: A 16KB | B 16KB
  GemmArgs ga = blockIdx.z == 0 ? g0 : (blockIdx.z == 1 ? g1 : g2);

  const int tid = threadIdx.x, lane = tid & 63, wid = tid >> 6;
  const int lrow = lane & 15, lko = (lane >> 4) * 8, rbase = (lane >> 4) * 4;
  const int m0 = blockIdx.x * 128, n0 = blockIdx.y * 128;
  const size_t ldb = (size_t)K * 2;

  const int srow = lane >> 3;                       // row within 8-row call
  const int c8 = lane & 7;
  const int sca = (c8 * 16) ^ (srow << 4);          // pre-swizzled source col (gload16)
  const char* Bb = (const char*)ga.B + (size_t)(n0 + wid * 32 + srow) * ldb + sca;
  const char* AbBf = (const char*)ga.A + (size_t)(m0 + wid * 32 + srow) * ldb + sca;
  const float* AbF = (const float*)ga.A + (size_t)(m0 + wid * 32 + srow) * K + c8 * 8;
  const int sdst = wid * 32 * 128;                  // wave's LDS row base (bytes)
  const uint32_t adst = swz128(wid * 32 + srow, c8 * 16);  // swizzled A dest (+j*1024)

  f32x4 acc[4][4];
  const f32x4 fz = {0.f, 0.f, 0.f, 0.f};
#pragma unroll
  for (int m = 0; m < 4; ++m)
#pragma unroll
    for (int n = 0; n < 4; ++n) acc[m][n] = fz;

  const int wm = (wid >> 1) * 64, wn = (wid & 1) * 64;
  const int NKT = K >> 6;

  // prologue: stage tile 0 into buf 0
  if (AFP32) {
    float4 av[4][2];
#pragma unroll
    for (int j = 0; j < 4; ++j) {
      av[j][0] = *reinterpret_cast<const float4*>(AbF + (size_t)j * 8 * K);
      av[j][1] = *reinterpret_cast<const float4*>(AbF + (size_t)j * 8 * K + 4);
      gload16(&lds[0][16384 + sdst + j * 1024], Bb + (size_t)j * 8 * ldb);
    }
#pragma unroll
    for (int j = 0; j < 4; ++j)
      *reinterpret_cast<bf16x8*>(&lds[0][adst + j * 1024]) = cvt8(av[j][0], av[j][1]);
  } else {
#pragma unroll
    for (int j = 0; j < 4; ++j) {
      gload16(&lds[0][sdst + j * 1024], AbBf + (size_t)j * 8 * ldb);
      gload16(&lds[0][16384 + sdst + j * 1024], Bb + (size_t)j * 8 * ldb);
    }
  }
  barrier_vm0();   // tile 0 ready

  for (int kt = 0; kt < NKT; ++kt) {
    const int c = kt & 1;
    const bool pre = (kt + 1 < NKT);
    float4 av[4][2];
    if (pre) {  // issue next-tile loads before compute (T14 / dbuf)
      if (AFP32) {
        const float* As = AbF + (size_t)(kt + 1) * 64;
#pragma unroll
        for (int j = 0; j < 4; ++j) {
          av[j][0] = *reinterpret_cast<const float4*>(As + (size_t)j * 8 * K);
          av[j][1] = *reinterpret_cast<const float4*>(As + (size_t)j * 8 * K + 4);
          gload16(&lds[c ^ 1][16384 + sdst + j * 1024], Bb + (size_t)j * 8 * ldb + (size_t)(kt + 1) * 128);
        }
      } else {
        const size_t koff = (size_t)(kt + 1) * 128;
#pragma unroll
        for (int j = 0; j < 4; ++j) {
          gload16(&lds[c ^ 1][sdst + j * 1024], AbBf + (size_t)j * 8 * ldb + koff);
          gload16(&lds[c ^ 1][16384 + sdst + j * 1024], Bb + (size_t)j * 8 * ldb + koff);
        }
      }
    }
    const char* lA = lds[c];
    const char* lB = lds[c] + 16384;
#pragma unroll
    for (int kk = 0; kk < 64; kk += 32) {
      bf16x8 af[4], bf[4];
#pragma unroll
      for (int m = 0; m < 4; ++m)
        af[m] = *reinterpret_cast<const bf16x8*>(&lA[swz128(wm + m * 16 + lrow, (kk + lko) * 2)]);
#pragma unroll
      for (int n = 0; n < 4; ++n)
        bf[n] = *reinterpret_cast<const bf16x8*>(&lB[swz128(wn + n * 16 + lrow, (kk + lko) * 2)]);
      __builtin_amdgcn_s_setprio(1);
#pragma unroll
      for (int m = 0; m < 4; ++m)
#pragma unroll
        for (int n = 0; n < 4; ++n)
          acc[m][n] = __builtin_amdgcn_mfma_f32_16x16x32_bf16(af[m], bf[n], acc[m][n], 0, 0, 0);
      __builtin_amdgcn_s_setprio(0);
    }
    if (AFP32 && pre) {  // write A tile kt+1 (compiler waits on av regs)
#pragma unroll
      for (int j = 0; j < 4; ++j)
        *reinterpret_cast<bf16x8*>(&lds[c ^ 1][adst + j * 1024]) = cvt8(av[j][0], av[j][1]);
    }
    barrier_vm0();  // B gloads complete + ds ops retired -> bufs swap safely
  }

  if (ga.mode == 2) {
#pragma unroll
    for (int m = 0; m < 4; ++m)
#pragma unroll
      for (int n = 0; n < 4; ++n) {
        const int col = n0 + wn + n * 16 + lrow;
        const float bv = ga.bias[col];
#pragma unroll
        for (int r = 0; r < 4; ++r) {
          const int row = m0 + wm + m * 16 + rbase + r;
          reinterpret_cast<float*>(ga.out)[(size_t)row * D_MODEL + col] = acc[m][n][r] + bv;
        }
      }
  } else if (ga.mode == 0) {
#pragma unroll
    for (int m = 0; m < 4; ++m)
#pragma unroll
      for (int n = 0; n < 4; ++n) {
        const int col = n0 + wn + n * 16 + lrow;
        const float bv = ga.bias[col];
        const int h = col >> 7, hd = col & 127;
#pragma unroll
        for (int r = 0; r < 4; ++r) {
          const int row = m0 + wm + m * 16 + rbase + r;
          const int b = row >> 11, s = row & 2047;
          reinterpret_cast<__hip_bfloat16*>(ga.out)[((size_t)(b * NHEAD + h) * SEQ + s) * HDIM + hd] =
              __float2bfloat16(acc[m][n][r] + bv);
        }
      }
  } else {
#pragma unroll
    for (int m = 0; m < 4; ++m)
#pragma unroll
      for (int n = 0; n < 4; ++n) {
        const int col = n0 + wn + n * 16 + lrow;
        const float bv = ga.bias[col];
        const int h = col >> 7, hd = col & 127;
#pragma unroll
        for (int r = 0; r < 4; ++r) {
          const int row = m0 + wm + m * 16 + rbase + r;
          const int b = row >> 11, s = row & 2047;
          reinterpret_cast<__hip_bfloat16*>(ga.out)[((size_t)(b * NHEAD + h) * HDIM + hd) * SEQ + s] =
              __float2bfloat16(acc[m][n][r] + bv);
        }
      }
  }
}

// ---------------- fused ReLU attention (r6-proven: counted-vmcnt barriers) ----------------
__global__ __launch_bounds__(512)
void attn_v2(const __hip_bfloat16* __restrict__ Qh,   // [bh][s][hd]
             const __hip_bfloat16* __restrict__ Kh,   // [bh][s][hd]
             const __hip_bfloat16* __restrict__ Vt,   // [bh][hd][s]
             float* __restrict__ attn,                // [bh][q][k]
             __hip_bfloat16* __restrict__ ctx) {      // [b][s][h*128+hd]
  __shared__ char ldsK[2][KVBLK * 256];
  __shared__ char ldsV[2][HDIM * 128];
  __shared__ char ldsP[128 * 128];

  const int tid = threadIdx.x, lane = tid & 63, wid = tid >> 6;
  const int lrow = lane & 15, lko = (lane >> 4) * 8, rbase = (lane >> 4) * 4;
  const int wqq = (wid >> 1) * 32;
  const int wqk = (wid & 1) * 32;
  const int whd = (wid & 1) * 64;

  const int raw = blockIdx.x;
  const int xcd = raw & 7, slot = raw >> 3;
  const int bh = xcd * 2 + (slot >> 4);
  const int q0 = (slot & 15) * 128;

  const char* Kg = (const char*)Kh + (size_t)bh * SEQ * HDIM * 2;
  const char* Vg = (const char*)Vt + (size_t)bh * HDIM * SEQ * 2;
  const __hip_bfloat16* Qg = Qh + ((size_t)bh * SEQ + q0) * HDIM;
  float* attnb = attn + ((size_t)bh * SEQ + q0) * SEQ;

  const int krl = lane >> 4;
  const int kcb = (lane & 15) * 16;
  const int vrl = lane >> 3;
  const int vsc = ((lane & 7) * 16) ^ (vrl << 4);

#pragma unroll
  for (int j = 0; j < 2; ++j) {
    const int rr = wid * 8 + j * 4 + krl;
    gload16((char*)ldsK[0] + (wid * 8 + j * 4) * 256,
            Kg + (size_t)rr * 256 + (kcb ^ ((rr & 7) << 4)));
    const int rv = wid * 16 + j * 8 + vrl;
    gload16((char*)ldsV[0] + (wid * 16 + j * 8) * 128,
            Vg + (size_t)rv * (SEQ * 2) + vsc);
  }

  bf16x8 qf[2][4];
#pragma unroll
  for (int m = 0; m < 2; ++m)
#pragma unroll
    for (int kk = 0; kk < 4; ++kk)
      qf[m][kk] = *reinterpret_cast<const bf16x8*>(
          Qg + (size_t)(wqq + m * 16 + lrow) * HDIM + kk * 32 + lko);

  f32x4 cacc[2][4];
  const f32x4 fz = {0.f, 0.f, 0.f, 0.f};
#pragma unroll
  for (int m = 0; m < 2; ++m)
#pragma unroll
    for (int n = 0; n < 4; ++n) cacc[m][n] = fz;

  const float scale = 0.08838834764831845f;  // 1/sqrt(128)
  __syncthreads();

  for (int t = 0; t < NT; ++t) {
    const int b = t & 1;
    if (t + 1 < NT) {
#pragma unroll
      for (int j = 0; j < 2; ++j) {
        const int rr = wid * 8 + j * 4 + krl;
        gload16((char*)ldsK[b ^ 1] + (wid * 8 + j * 4) * 256,
                Kg + (size_t)((t + 1) * KVBLK + rr) * 256 + (kcb ^ ((rr & 7) << 4)));
        const int rv = wid * 16 + j * 8 + vrl;
        gload16((char*)ldsV[b ^ 1] + (wid * 16 + j * 8) * 128,
                Vg + (size_t)rv * (SEQ * 2) + (t + 1) * 128 + vsc);
      }
    }

    f32x4 sacc[2][2];
#pragma unroll
    for (int m = 0; m < 2; ++m)
#pragma unroll
      for (int n = 0; n < 2; ++n) sacc[m][n] = fz;
    __builtin_amdgcn_s_setprio(1);
#pragma unroll
    for (int kk = 0; kk < 4; ++kk) {
      bf16x8 kf[2];
#pragma unroll
      for (int n = 0; n < 2; ++n)
        kf[n] = *reinterpret_cast<const bf16x8*>(
            &ldsK[b][swz256(wqk + n * 16 + lrow, (kk * 32 + lko) * 2)]);
#pragma unroll
      for (int m = 0; m < 2; ++m)
#pragma unroll
        for (int n = 0; n < 2; ++n)
          sacc[m][n] = __builtin_amdgcn_mfma_f32_16x16x32_bf16(qf[m][kk], kf[n], sacc[m][n], 0, 0, 0);
    }
    __builtin_amdgcn_s_setprio(0);

#pragma unroll
    for (int m = 0; m < 2; ++m)
#pragma unroll
      for (int n = 0; n < 2; ++n)
#pragma unroll
        for (int r = 0; r < 4; ++r) {
          const int ql = wqq + m * 16 + rbase + r;
          const int kl = wqk + n * 16 + lrow;
          const float s = fmaxf(sacc[m][n][r] * scale, 0.f);
          attnb[(size_t)ql * SEQ + t * KVBLK + kl] = s;
          *reinterpret_cast<__hip_bfloat16*>(&ldsP[swz128(ql, kl * 2)]) = __float2bfloat16(s);
        }
    barrier_lgkm();

    __builtin_amdgcn_s_setprio(1);
#pragma unroll
    for (int kk = 0; kk < 2; ++kk) {
      bf16x8 pf[2], vf[4];
#pragma unroll
      for (int m = 0; m < 2; ++m)
        pf[m] = *reinterpret_cast<const bf16x8*>(
            &ldsP[swz128(wqq + m * 16 + lrow, (kk * 32 + lko) * 2)]);
#pragma unroll
      for (int n = 0; n < 4; ++n)
        vf[n] = *reinterpret_cast<const bf16x8*>(
            &ldsV[b][swz128(whd + n * 16 + lrow, (kk * 32 + lko) * 2)]);
#pragma unroll
      for (int m = 0; m < 2; ++m)
#pragma unroll
        for (int n = 0; n < 4; ++n)
          cacc[m][n] = __builtin_amdgcn_mfma_f32_16x16x32_bf16(pf[m], vf[n], cacc[m][n], 0, 0, 0);
    }
    __builtin_amdgcn_s_setprio(0);
    barrier_vm16();
  }

  const int bb = bh >> 3, h = bh & 7;
#pragma unroll
  for (int m = 0; m < 2; ++m)
#pragma unroll
    for (int n = 0; n < 4; ++n)
#pragma unroll
      for (int r = 0; r < 4; ++r) {
        const int srow = q0 + wqq + m * 16 + rbase + r;
        const int hd = whd + n * 16 + lrow;
        ctx[((size_t)(bb * SEQ + srow)) * D_MODEL + h * HDIM + hd] =
            __float2bfloat16(cacc[m][n][r]);
      }
}

extern "C" void kernel_launch(void* const* d_in, const int* in_sizes, int n_in,
                              void* d_out, int out_size, void* d_ws, size_t ws_size,
                              hipStream_t stream) {
  const float* q  = (const float*)d_in[0];
  const float* k  = (const float*)d_in[1];
  const float* v  = (const float*)d_in[2];
  const float* Wq = (const float*)d_in[3];
  const float* bq = (const float*)d_in[4];
  const float* Wk = (const float*)d_in[5];
  const float* bk = (const float*)d_in[6];
  const float* Wv = (const float*)d_in[7];
  const float* bv = (const float*)d_in[8];
  const float* Wo = (const float*)d_in[9];
  const float* bo = (const float*)d_in[10];

  char* ws = (char*)d_ws;
  const size_t NE = (size_t)MTOT * D_MODEL;     // 4194304
  const size_t WE = (size_t)D_MODEL * D_MODEL;  // 1048576
  __hip_bfloat16* Wqt = (__hip_bfloat16*)ws;
  __hip_bfloat16* Wkt = Wqt + WE;
  __hip_bfloat16* Wvt = Wkt + WE;
  __hip_bfloat16* Wot = Wvt + WE;
  __hip_bfloat16* Qh  = Wot + WE;
  __hip_bfloat16* Kh  = Qh + NE;
  __hip_bfloat16* Vt  = Kh + NE;
  __hip_bfloat16* ctx = Vt + NE;

  transpose4<<<dim3(32, 32, 4), dim3(32, 8), 0, stream>>>(Wq, Wk, Wv, Wo, Wqt, Wkt, Wvt, Wot);

  GemmArgs gq{q, Wqt, bq, Qh, 0};
  GemmArgs gk{k, Wkt, bk, Kh, 0};
  GemmArgs gv{v, Wvt, bv, Vt, 1};
  gemm_gl<true><<<dim3(32, 8, 3), 256, 0, stream>>>(gq, gk, gv, D_MODEL);

  float* outp  = (float*)d_out;
  float* attnp = outp + NE;
  attn_v2<<<256, 512, 0, stream>>>(Qh, Kh, Vt, attnp, ctx);

  GemmArgs go{ctx, Wot, bo, d_out, 2};
  gemm_gl<false><<<dim3(32, 8, 1), 256, 0, stream>>>(go, go, go, D_MODEL);
}

// Round 10
// 150.059 us; speedup vs baseline: 1.1180x; 1.1180x over previous
//
#include <hip/hip_runtime.h>
#include <hip/hip_bf16.h>
#include <stdint.h>

#define D_MODEL 1024
#define NHEAD 8
#define HDIM 128
#define BATCH 2
#define SEQ 2048
#define MTOT (BATCH*SEQ)   // 4096
#define KVBLK 64
#define NT (SEQ/KVBLK)     // 32

typedef __attribute__((ext_vector_type(4))) float f32x4;
typedef __attribute__((ext_vector_type(8))) short bf16x8;

// XOR swizzle: LDS(row, c) holds element (row, c ^ ((row&7)<<4)). Involution,
// used identically on the pre-swizzled global source and the ds_read side (G21).
__device__ __forceinline__ uint32_t swz128(uint32_t row, uint32_t cb) {
  return row * 128u + (cb ^ ((row & 7u) << 4));
}
__device__ __forceinline__ uint32_t swz256(uint32_t row, uint32_t cb) {
  return row * 256u + (cb ^ ((row & 7u) << 4));
}

// async global->LDS, 16B per lane
__device__ __forceinline__ void gload16(void* lds, const void* g) {
  __builtin_amdgcn_global_load_lds(
      reinterpret_cast<const __attribute__((address_space(1))) uint32_t*>(
          reinterpret_cast<uintptr_t>(g)),
      reinterpret_cast<__attribute__((address_space(3))) uint32_t*>(
          (uint32_t)reinterpret_cast<uintptr_t>(lds)),
      16, 0, 0);
}

// Counted barriers (T4).
__device__ __forceinline__ void barrier_lgkm() {
  asm volatile("s_waitcnt lgkmcnt(0)\n\ts_barrier" ::: "memory");
}
__device__ __forceinline__ void barrier_vm16() {
  asm volatile("s_waitcnt vmcnt(16) lgkmcnt(0)\n\ts_barrier" ::: "memory");
}
__device__ __forceinline__ void barrier_vm0() {
  asm volatile("s_waitcnt vmcnt(0) lgkmcnt(0)\n\ts_barrier" ::: "memory");
}

// ---------------- prep: cast q/k/v fp32->bf16 (blocks [0,6144)) AND
// transpose+cast 4 weights (blocks [6144,10240)), one launch ----------------
__global__ __launch_bounds__(256)
void prep(const float* __restrict__ q, const float* __restrict__ k,
          const float* __restrict__ v, __hip_bfloat16* __restrict__ qkv_out,
          const float* __restrict__ w0, const float* __restrict__ w1,
          const float* __restrict__ w2, const float* __restrict__ w3,
          __hip_bfloat16* __restrict__ t0, __hip_bfloat16* __restrict__ t1,
          __hip_bfloat16* __restrict__ t2, __hip_bfloat16* __restrict__ t3) {
  const int bid = blockIdx.x;
  const int tid = threadIdx.x;
  if (bid < 6144) {
    const int which = bid >> 11;          // 0..2
    const int blk = bid & 2047;
    const float* src = which == 0 ? q : (which == 1 ? k : v);
    const size_t NE = (size_t)MTOT * D_MODEL;
    size_t i = ((size_t)blk * 256 + tid) * 8;
    float4 a = *reinterpret_cast<const float4*>(src + i);
    float4 b = *reinterpret_cast<const float4*>(src + i + 4);
    __hip_bfloat16 o[8] = {__float2bfloat16(a.x), __float2bfloat16(a.y),
                           __float2bfloat16(a.z), __float2bfloat16(a.w),
                           __float2bfloat16(b.x), __float2bfloat16(b.y),
                           __float2bfloat16(b.z), __float2bfloat16(b.w)};
    *reinterpret_cast<uint4*>(qkv_out + which * NE + i) =
        *reinterpret_cast<const uint4*>(o);
  } else {
    const int rb = bid - 6144;
    const int z = rb >> 10;               // 0..3
    const int rem = rb & 1023;
    const float* W = z == 0 ? w0 : z == 1 ? w1 : z == 2 ? w2 : w3;
    __hip_bfloat16* Wt = z == 0 ? t0 : z == 1 ? t1 : z == 2 ? t2 : t3;
    __shared__ float t[32][33];
    const int x = tid & 31, y = tid >> 5;  // 32 x 8
    const int n0 = (rem & 31) * 32, k0 = (rem >> 5) * 32;
#pragma unroll
    for (int i = 0; i < 4; ++i)
      t[y + i * 8][x] = W[(size_t)(k0 + y + i * 8) * D_MODEL + n0 + x];
    __syncthreads();
#pragma unroll
    for (int i = 0; i < 4; ++i)
      Wt[(size_t)(n0 + y + i * 8) * D_MODEL + k0 + x] = __float2bfloat16(t[x][y + i * 8]);
  }
}

struct GemmArgs {
  const __hip_bfloat16* A;   // [M][K]
  const __hip_bfloat16* B;   // [N][K]  (W^T)
  const float* bias;         // [N]
  void* out;
  int mode;  // 0: bf16 [bh][s][hd]; 1: bf16 [bh][hd][s]; 2: fp32 [row][col]
};

// ---------------- 128x128 bf16 GEMM, double-buffered prefetch K-loop (r8-proven) ----------------
__global__ __launch_bounds__(256)
void gemm_gl(GemmArgs g0, GemmArgs g1, GemmArgs g2, int K) {
  __shared__ char lds[2][32768];   // per buf: A 16KB | B 16KB
  GemmArgs ga = blockIdx.z == 0 ? g0 : (blockIdx.z == 1 ? g1 : g2);

  const int tid = threadIdx.x, lane = tid & 63, wid = tid >> 6;
  const int lrow = lane & 15, lko = (lane >> 4) * 8, rbase = (lane >> 4) * 4;
  const int m0 = blockIdx.x * 128, n0 = blockIdx.y * 128;
  const size_t ldb = (size_t)K * 2;

  const int srow = lane >> 3;                       // row within 8-row call
  const int sca = ((lane & 7) * 16) ^ (srow << 4);  // pre-swizzled source col
  const char* Ab = (const char*)ga.A + (size_t)(m0 + wid * 32 + srow) * ldb + sca;
  const char* Bb = (const char*)ga.B + (size_t)(n0 + wid * 32 + srow) * ldb + sca;
  const int sdst = wid * 32 * 128;                  // wave's LDS row base (bytes)

  f32x4 acc[4][4];
  const f32x4 fz = {0.f, 0.f, 0.f, 0.f};
#pragma unroll
  for (int m = 0; m < 4; ++m)
#pragma unroll
    for (int n = 0; n < 4; ++n) acc[m][n] = fz;

  const int wm = (wid >> 1) * 64, wn = (wid & 1) * 64;
  const int NKT = K >> 6;

  // prologue: stage tile 0 into buf 0
#pragma unroll
  for (int i = 0; i < 4; ++i) {
    gload16(&lds[0][sdst + i * 8 * 128], Ab + (size_t)i * 8 * ldb);
    gload16(&lds[0][16384 + sdst + i * 8 * 128], Bb + (size_t)i * 8 * ldb);
  }
  barrier_vm0();   // tile 0 ready

  for (int kt = 0; kt < NKT; ++kt) {
    const int c = kt & 1;
    if (kt + 1 < NKT) {  // prefetch next tile into other buffer
      const size_t koff = (size_t)(kt + 1) * 128;
#pragma unroll
      for (int i = 0; i < 4; ++i) {
        gload16(&lds[c ^ 1][sdst + i * 8 * 128], Ab + (size_t)i * 8 * ldb + koff);
        gload16(&lds[c ^ 1][16384 + sdst + i * 8 * 128], Bb + (size_t)i * 8 * ldb + koff);
      }
    }
    const char* lA = lds[c];
    const char* lB = lds[c] + 16384;
#pragma unroll
    for (int kk = 0; kk < 64; kk += 32) {
      bf16x8 af[4], bf[4];
#pragma unroll
      for (int m = 0; m < 4; ++m)
        af[m] = *reinterpret_cast<const bf16x8*>(&lA[swz128(wm + m * 16 + lrow, (kk + lko) * 2)]);
#pragma unroll
      for (int n = 0; n < 4; ++n)
        bf[n] = *reinterpret_cast<const bf16x8*>(&lB[swz128(wn + n * 16 + lrow, (kk + lko) * 2)]);
      __builtin_amdgcn_s_setprio(1);
#pragma unroll
      for (int m = 0; m < 4; ++m)
#pragma unroll
        for (int n = 0; n < 4; ++n)
          acc[m][n] = __builtin_amdgcn_mfma_f32_16x16x32_bf16(af[m], bf[n], acc[m][n], 0, 0, 0);
      __builtin_amdgcn_s_setprio(0);
    }
    barrier_vm0();  // prefetch complete + all ds_reads retired -> bufs swap safely
  }

  if (ga.mode == 2) {
#pragma unroll
    for (int m = 0; m < 4; ++m)
#pragma unroll
      for (int n = 0; n < 4; ++n) {
        const int col = n0 + wn + n * 16 + lrow;
        const float bv = ga.bias[col];
#pragma unroll
        for (int r = 0; r < 4; ++r) {
          const int row = m0 + wm + m * 16 + rbase + r;
          reinterpret_cast<float*>(ga.out)[(size_t)row * D_MODEL + col] = acc[m][n][r] + bv;
        }
      }
  } else if (ga.mode == 0) {
#pragma unroll
    for (int m = 0; m < 4; ++m)
#pragma unroll
      for (int n = 0; n < 4; ++n) {
        const int col = n0 + wn + n * 16 + lrow;
        const float bv = ga.bias[col];
        const int h = col >> 7, hd = col & 127;
#pragma unroll
        for (int r = 0; r < 4; ++r) {
          const int row = m0 + wm + m * 16 + rbase + r;
          const int b = row >> 11, s = row & 2047;
          reinterpret_cast<__hip_bfloat16*>(ga.out)[((size_t)(b * NHEAD + h) * SEQ + s) * HDIM + hd] =
              __float2bfloat16(acc[m][n][r] + bv);
        }
      }
  } else {
#pragma unroll
    for (int m = 0; m < 4; ++m)
#pragma unroll
      for (int n = 0; n < 4; ++n) {
        const int col = n0 + wn + n * 16 + lrow;
        const float bv = ga.bias[col];
        const int h = col >> 7, hd = col & 127;
#pragma unroll
        for (int r = 0; r < 4; ++r) {
          const int row = m0 + wm + m * 16 + rbase + r;
          const int b = row >> 11, s = row & 2047;
          reinterpret_cast<__hip_bfloat16*>(ga.out)[((size_t)(b * NHEAD + h) * HDIM + hd) * SEQ + s] =
              __float2bfloat16(acc[m][n][r] + bv);
        }
      }
  }
}

// ---------------- fused ReLU attention (r6-proven: counted-vmcnt barriers) ----------------
__global__ __launch_bounds__(512)
void attn_v2(const __hip_bfloat16* __restrict__ Qh,   // [bh][s][hd]
             const __hip_bfloat16* __restrict__ Kh,   // [bh][s][hd]
             const __hip_bfloat16* __restrict__ Vt,   // [bh][hd][s]
             float* __restrict__ attn,                // [bh][q][k]
             __hip_bfloat16* __restrict__ ctx) {      // [b][s][h*128+hd]
  __shared__ char ldsK[2][KVBLK * 256];
  __shared__ char ldsV[2][HDIM * 128];
  __shared__ char ldsP[128 * 128];

  const int tid = threadIdx.x, lane = tid & 63, wid = tid >> 6;
  const int lrow = lane & 15, lko = (lane >> 4) * 8, rbase = (lane >> 4) * 4;
  const int wqq = (wid >> 1) * 32;
  const int wqk = (wid & 1) * 32;
  const int whd = (wid & 1) * 64;

  const int raw = blockIdx.x;
  const int xcd = raw & 7, slot = raw >> 3;
  const int bh = xcd * 2 + (slot >> 4);
  const int q0 = (slot & 15) * 128;

  const char* Kg = (const char*)Kh + (size_t)bh * SEQ * HDIM * 2;
  const char* Vg = (const char*)Vt + (size_t)bh * HDIM * SEQ * 2;
  const __hip_bfloat16* Qg = Qh + ((size_t)bh * SEQ + q0) * HDIM;
  float* attnb = attn + ((size_t)bh * SEQ + q0) * SEQ;

  const int krl = lane >> 4;
  const int kcb = (lane & 15) * 16;
  const int vrl = lane >> 3;
  const int vsc = ((lane & 7) * 16) ^ (vrl << 4);

#pragma unroll
  for (int j = 0; j < 2; ++j) {
    const int rr = wid * 8 + j * 4 + krl;
    gload16((char*)ldsK[0] + (wid * 8 + j * 4) * 256,
            Kg + (size_t)rr * 256 + (kcb ^ ((rr & 7) << 4)));
    const int rv = wid * 16 + j * 8 + vrl;
    gload16((char*)ldsV[0] + (wid * 16 + j * 8) * 128,
            Vg + (size_t)rv * (SEQ * 2) + vsc);
  }

  bf16x8 qf[2][4];
#pragma unroll
  for (int m = 0; m < 2; ++m)
#pragma unroll
    for (int kk = 0; kk < 4; ++kk)
      qf[m][kk] = *reinterpret_cast<const bf16x8*>(
          Qg + (size_t)(wqq + m * 16 + lrow) * HDIM + kk * 32 + lko);

  f32x4 cacc[2][4];
  const f32x4 fz = {0.f, 0.f, 0.f, 0.f};
#pragma unroll
  for (int m = 0; m < 2; ++m)
#pragma unroll
    for (int n = 0; n < 4; ++n) cacc[m][n] = fz;

  const float scale = 0.08838834764831845f;  // 1/sqrt(128)
  __syncthreads();

  for (int t = 0; t < NT; ++t) {
    const int b = t & 1;
    if (t + 1 < NT) {
#pragma unroll
      for (int j = 0; j < 2; ++j) {
        const int rr = wid * 8 + j * 4 + krl;
        gload16((char*)ldsK[b ^ 1] + (wid * 8 + j * 4) * 256,
                Kg + (size_t)((t + 1) * KVBLK + rr) * 256 + (kcb ^ ((rr & 7) << 4)));
        const int rv = wid * 16 + j * 8 + vrl;
        gload16((char*)ldsV[b ^ 1] + (wid * 16 + j * 8) * 128,
                Vg + (size_t)rv * (SEQ * 2) + (t + 1) * 128 + vsc);
      }
    }

    f32x4 sacc[2][2];
#pragma unroll
    for (int m = 0; m < 2; ++m)
#pragma unroll
      for (int n = 0; n < 2; ++n) sacc[m][n] = fz;
    __builtin_amdgcn_s_setprio(1);
#pragma unroll
    for (int kk = 0; kk < 4; ++kk) {
      bf16x8 kf[2];
#pragma unroll
      for (int n = 0; n < 2; ++n)
        kf[n] = *reinterpret_cast<const bf16x8*>(
            &ldsK[b][swz256(wqk + n * 16 + lrow, (kk * 32 + lko) * 2)]);
#pragma unroll
      for (int m = 0; m < 2; ++m)
#pragma unroll
        for (int n = 0; n < 2; ++n)
          sacc[m][n] = __builtin_amdgcn_mfma_f32_16x16x32_bf16(qf[m][kk], kf[n], sacc[m][n], 0, 0, 0);
    }
    __builtin_amdgcn_s_setprio(0);

#pragma unroll
    for (int m = 0; m < 2; ++m)
#pragma unroll
      for (int n = 0; n < 2; ++n)
#pragma unroll
        for (int r = 0; r < 4; ++r) {
          const int ql = wqq + m * 16 + rbase + r;
          const int kl = wqk + n * 16 + lrow;
          const float s = fmaxf(sacc[m][n][r] * scale, 0.f);
          attnb[(size_t)ql * SEQ + t * KVBLK + kl] = s;
          *reinterpret_cast<__hip_bfloat16*>(&ldsP[swz128(ql, kl * 2)]) = __float2bfloat16(s);
        }
    barrier_lgkm();

    __builtin_amdgcn_s_setprio(1);
#pragma unroll
    for (int kk = 0; kk < 2; ++kk) {
      bf16x8 pf[2], vf[4];
#pragma unroll
      for (int m = 0; m < 2; ++m)
        pf[m] = *reinterpret_cast<const bf16x8*>(
            &ldsP[swz128(wqq + m * 16 + lrow, (kk * 32 + lko) * 2)]);
#pragma unroll
      for (int n = 0; n < 4; ++n)
        vf[n] = *reinterpret_cast<const bf16x8*>(
            &ldsV[b][swz128(whd + n * 16 + lrow, (kk * 32 + lko) * 2)]);
#pragma unroll
      for (int m = 0; m < 2; ++m)
#pragma unroll
        for (int n = 0; n < 4; ++n)
          cacc[m][n] = __builtin_amdgcn_mfma_f32_16x16x32_bf16(pf[m], vf[n], cacc[m][n], 0, 0, 0);
    }
    __builtin_amdgcn_s_setprio(0);
    barrier_vm16();
  }

  const int bb = bh >> 3, h = bh & 7;
#pragma unroll
  for (int m = 0; m < 2; ++m)
#pragma unroll
    for (int n = 0; n < 4; ++n)
#pragma unroll
      for (int r = 0; r < 4; ++r) {
        const int srow = q0 + wqq + m * 16 + rbase + r;
        const int hd = whd + n * 16 + lrow;
        ctx[((size_t)(bb * SEQ + srow)) * D_MODEL + h * HDIM + hd] =
            __float2bfloat16(cacc[m][n][r]);
      }
}

extern "C" void kernel_launch(void* const* d_in, const int* in_sizes, int n_in,
                              void* d_out, int out_size, void* d_ws, size_t ws_size,
                              hipStream_t stream) {
  const float* q  = (const float*)d_in[0];
  const float* k  = (const float*)d_in[1];
  const float* v  = (const float*)d_in[2];
  const float* Wq = (const float*)d_in[3];
  const float* bq = (const float*)d_in[4];
  const float* Wk = (const float*)d_in[5];
  const float* bk = (const float*)d_in[6];
  const float* Wv = (const float*)d_in[7];
  const float* bv = (const float*)d_in[8];
  const float* Wo = (const float*)d_in[9];
  const float* bo = (const float*)d_in[10];

  char* ws = (char*)d_ws;
  const size_t NE = (size_t)MTOT * D_MODEL;     // 4194304
  const size_t WE = (size_t)D_MODEL * D_MODEL;  // 1048576
  __hip_bfloat16* qb  = (__hip_bfloat16*)ws;
  __hip_bfloat16* kb  = qb + NE;
  __hip_bfloat16* vb  = kb + NE;
  __hip_bfloat16* Wqt = vb + NE;
  __hip_bfloat16* Wkt = Wqt + WE;
  __hip_bfloat16* Wvt = Wkt + WE;
  __hip_bfloat16* Wot = Wvt + WE;
  __hip_bfloat16* Qh  = Wot + WE;
  __hip_bfloat16* Kh  = Qh + NE;
  __hip_bfloat16* Vt  = Kh + NE;
  __hip_bfloat16* ctx = Vt + NE;

  prep<<<10240, 256, 0, stream>>>(q, k, v, qb, Wq, Wk, Wv, Wo, Wqt, Wkt, Wvt, Wot);

  GemmArgs gq{qb, Wqt, bq, Qh, 0};
  GemmArgs gk{kb, Wkt, bk, Kh, 0};
  GemmArgs gv{vb, Wvt, bv, Vt, 1};
  gemm_gl<<<dim3(32, 8, 3), 256, 0, stream>>>(gq, gk, gv, D_MODEL);

  float* outp  = (float*)d_out;
  float* attnp = outp + NE;
  attn_v2<<<256, 512, 0, stream>>>(Qh, Kh, Vt, attnp, ctx);

  GemmArgs go{ctx, Wot, bo, d_out, 2};
  gemm_gl<<<dim3(32, 8, 1), 256, 0, stream>>>(go, go, go, D_MODEL);
}